// Round 9
// baseline (26.875 us; speedup 1.0000x reference)
//
#include <hip/hip_runtime.h>
#include <hip/hip_fp16.h>
#include <math.h>

// Problem constants (match reference)
#define Bb   16
#define Cc   3
#define Hh   64
#define Ww   64
#define Kk   32
#define Ss   32
#define OHh  60
#define OWw  60
#define Pp   3600
#define OHSUB 15           // output rows per block (4 strips)
#define ROWS 19            // staged rows per block: 15 + R-1
#define NGRP 225           // 15 rows * 15 groups of 4 columns
#define TPB  256

// fp16 LDS layout (dword units): row = 33 dwords (66 halfs: 64 data + pad).
// Bank stride per row = 33 mod 32 = 1 -> oh-major lanes are conflict-free.
// Two copies: S0[p] = x[p], S1[p] = x[p+1]; a leaf at col w reads copy (w&1)
// starting at half (w - (w&1)) -> every gather is one dword pair (ds_read2_b32).
#define DWROW  33
#define DWC    (ROWS * DWROW)   // 627 dwords per channel
#define DWCOPY (Cc * DWC)       // 1881 dwords per copy

typedef float vf4 __attribute__((ext_vector_type(4)));
typedef float vf4u __attribute__((ext_vector_type(4), aligned(4)));

#define SB __builtin_amdgcn_sched_barrier(0)

static __device__ __forceinline__ vf4 vsplat(float s) { return (vf4){s, s, s, s}; }

// combine: y = c0 + a*dA + b*dB + a*b*dAB  (c = {c0, dA, dB, dAB})
static __device__ __forceinline__ vf4 comb(vf4 a, vf4 b, vf4 c) {
    const vf4 t = __builtin_elementwise_fma(b, vsplat(c.w), vsplat(c.y));
    const vf4 u = __builtin_elementwise_fma(b, vsplat(c.z), vsplat(c.x));
    return __builtin_elementwise_fma(a, t, u);
}

// pack two f32 -> one dword of two f16 (RTE)
static __device__ __forceinline__ unsigned int pkh(float lo, float hi) {
    __half2 h = __floats2half2_rn(lo, hi);
    return *reinterpret_cast<unsigned int*>(&h);
}

// ---------------- coef/base precompute kernel (per k, uniform data) --------
// ws layout per k (slot of 128 vf4 = 2 KB):
//   vf4 [0..62]  : folded node coefficients {c0, dA, dB, dAB}
//   int2[@vf4 64]: 32 leaf base dword-offsets into xsh
__global__ __launch_bounds__(128) void coef_kernel(
    const int* __restrict__ h_idx, const int* __restrict__ w_idx,
    const int* __restrict__ c_idx,
    const float* __restrict__ w0, const float* __restrict__ w1,
    const float* __restrict__ w2, const float* __restrict__ w3,
    const float* __restrict__ w4, const float* __restrict__ w5,
    float* __restrict__ ws)
{
    const int k = blockIdx.x;
    const int t = threadIdx.x;
    float* slot = ws + (k << 9);            // 128 vf4 = 512 floats per k

    if (t < 63) {
        const float* wp; int n;
        if      (t < 32) { wp = w0; n = t;      }
        else if (t < 48) { wp = w1; n = t - 32; }
        else if (t < 56) { wp = w2; n = t - 48; }
        else if (t < 60) { wp = w3; n = t - 56; }
        else if (t < 62) { wp = w4; n = t - 60; }
        else             { wp = w5; n = 0;      }
        const float* lg = wp + (n * Kk + k) * 16;
        float l[16];
        float m = lg[0];
        #pragma unroll
        for (int q = 0; q < 16; ++q) { l[q] = lg[q]; m = fmaxf(m, l[q]); }
        float e[16], s = 0.f;
        #pragma unroll
        for (int q = 0; q < 16; ++q) { e[q] = __expf(l[q] - m); s += e[q]; }
        const float inv = 1.f / s;
        float c0 = 0.f, c1 = 0.f, c2 = 0.f, c3 = 0.f;
        #pragma unroll
        for (int op = 0; op < 16; ++op) {
            if (op & 1) c0 += e[op];
            if (op & 2) c1 += e[op];
            if (op & 4) c2 += e[op];
            if (op & 8) c3 += e[op];
        }
        c0 *= inv; c1 *= inv; c2 *= inv; c3 *= inv;
        slot[t * 4 + 0] = c0;
        slot[t * 4 + 1] = c2 - c0;
        slot[t * 4 + 2] = c1 - c0;
        slot[t * 4 + 3] = c0 - c1 - c2 + c3;
    } else if (t >= 64 && t < 96) {
        const int leaf = t - 64;
        const int i0 = (0 * Kk + k) * Ss + leaf;
        const int i1 = (1 * Kk + k) * Ss + leaf;
        const int wA = w_idx[i0], sA = wA & 1;
        const int wB = w_idx[i1], sB = wB & 1;
        int2* bs = reinterpret_cast<int2*>(slot + 256);
        bs[leaf] = make_int2(
            sA * DWCOPY + c_idx[i0] * DWC + h_idx[i0] * DWROW + ((wA - sA) >> 1),
            sB * DWCOPY + c_idx[i1] * DWC + h_idx[i1] * DWROW + ((wB - sB) >> 1));
    }
}

// ---------------- main kernel ----------------------------------------------
// gather 4 consecutive px of one leaf-input: one dword pair from LDS
#define GATH(sbase, dst)                                                     \
    {                                                                        \
        const unsigned int lo = xsh[(sbase) + loff];                         \
        const unsigned int hi = xsh[(sbase) + loff + 1];                     \
        const __half2 hl = *reinterpret_cast<const __half2*>(&lo);           \
        const __half2 hh = *reinterpret_cast<const __half2*>(&hi);           \
        const float2 fl = __half22float2(hl);                                \
        const float2 fh = __half22float2(hh);                                \
        dst = (vf4){fl.x, fl.y, fh.x, fh.y};                                 \
    }

// load stage S's uniform data (SGPR-resident: coefs + leaf bases).
// Declared at OUTER scope (visible to the later STAGE(S)).
#define LOADC(S)                                                              \
    const vf4 c0_##S = ck[4*(S)],   c1_##S = ck[4*(S)+1];                     \
    const vf4 c2_##S = ck[4*(S)+2], c3_##S = ck[4*(S)+3];                     \
    const vf4 d0_##S = ck[32+2*(S)], d1_##S = ck[33+2*(S)];                   \
    const vf4 e0_##S = ck[48+(S)];                                            \
    const int2 b0_##S = bs[4*(S)],   b1_##S = bs[4*(S)+1];                    \
    const int2 b2_##S = bs[4*(S)+2], b3_##S = bs[4*(S)+3];

// One SUB4 stage: 8 LDS gathers then FMA cluster, SB-pinned boundary.
#define STAGE(S, FOLD)                                                        \
    vf4 t4_##S;                                                               \
    {                                                                         \
        vf4 A0, B0, A1, B1, A2, B2, A3, B3;                                   \
        GATH(b0_##S.x, A0); GATH(b0_##S.y, B0);                               \
        GATH(b1_##S.x, A1); GATH(b1_##S.y, B1);                               \
        GATH(b2_##S.x, A2); GATH(b2_##S.y, B2);                               \
        GATH(b3_##S.x, A3); GATH(b3_##S.y, B3);                               \
        const vf4 u0 = comb(A0, B0, c0_##S), u1 = comb(A1, B1, c1_##S);       \
        const vf4 u2 = comb(A2, B2, c2_##S), u3 = comb(A3, B3, c3_##S);       \
        t4_##S = comb(comb(u0, u1, d0_##S), comb(u2, u3, d1_##S), e0_##S);    \
        FOLD                                                                  \
        SB;                                                                   \
    }

__global__ __launch_bounds__(TPB) void logic_conv_kernel(
    const float* __restrict__ x,
    const float* __restrict__ cws,
    float* __restrict__ out)
{
    __shared__ unsigned int xsh[2 * DWCOPY];   // 15,048 B

    const int tid   = threadIdx.x;
    const int blk   = blockIdx.x;
    const int strip = blk & 3;
    const int k     = __builtin_amdgcn_readfirstlane((blk >> 2) & 31);
    const int b     = blk >> 7;
    const int oh0   = strip * OHSUB;

    const vf4*  ck = reinterpret_cast<const vf4*>(cws) + (k << 7);
    const int2* bs = reinterpret_cast<const int2*>(ck + 64);

    // ---- stage rows [oh0, oh0+19) of x[b] as fp16, two shifted copies ----
    const float* xb = x + b * (Cc * Hh * Ww);
    #pragma unroll
    for (int it = 0; it < 4; ++it) {
        const int flat = it * TPB + tid;           // chunk of 4 floats, 0..911
        if (flat < Cc * ROWS * 16) {
            const int c   = flat / (ROWS * 16);    // /304
            const int rem = flat - c * (ROWS * 16);
            const int r   = rem >> 4;
            const int w4i = rem & 15;
            const int w0c = w4i << 2;
            const float* src = xb + c * (Hh * Ww) + (oh0 + r) * Ww + w0c;
            const vf4u A = *reinterpret_cast<const vf4u*>(src);
            vf4u Bv;
            if (w4i < 15) Bv = *reinterpret_cast<const vf4u*>(src + 1);
            else          Bv = (vf4u){A.y, A.z, A.w, A.w};   // tail pad, never read
            const int di = c * DWC + r * DWROW + (w0c >> 1);
            xsh[di]              = pkh(A.x, A.y);
            xsh[di + 1]          = pkh(A.z, A.w);
            xsh[DWCOPY + di]     = pkh(Bv.x, Bv.y);
            xsh[DWCOPY + di + 1] = pkh(Bv.z, Bv.w);
        }
    }

    __syncthreads();

    // ---- main: one 4-px group per thread, oh-major (conflict-free) ----
    if (tid < NGRP) {
        const int oh   = tid % OHSUB;              // consecutive lanes -> rows
        const int owg  = tid / OHSUB;              // 0..14
        const int loff = oh * DWROW + (owg << 1);  // dword offset within copy

        vf4 t8a, t8b, t16a, t16b, y;
        LOADC(0)
        LOADC(1)
        STAGE(0, )
        LOADC(2)
        STAGE(1, t8a = comb(t4_0, t4_1, ck[56]);)
        LOADC(3)
        STAGE(2, )
        LOADC(4)
        STAGE(3, t8b = comb(t4_2, t4_3, ck[57]);
                 t16a = comb(t8a, t8b, ck[60]);)
        LOADC(5)
        STAGE(4, )
        LOADC(6)
        STAGE(5, t8a = comb(t4_4, t4_5, ck[58]);)
        LOADC(7)
        STAGE(6, )
        STAGE(7, t8b = comb(t4_6, t4_7, ck[59]);
                 t16b = comb(t8a, t8b, ck[61]);
                 y = comb(t16a, t16b, ck[62]);)

        float* outp = out + (b * Kk + k) * Pp + (oh0 + oh) * OWw + (owg << 2);
        *reinterpret_cast<vf4*>(outp) = y;
    }
}

extern "C" void kernel_launch(void* const* d_in, const int* in_sizes, int n_in,
                              void* d_out, int out_size, void* d_ws, size_t ws_size,
                              hipStream_t stream) {
    const float* x     = (const float*)d_in[0];
    const int*   h_idx = (const int*)d_in[1];
    const int*   w_idx = (const int*)d_in[2];
    const int*   c_idx = (const int*)d_in[3];
    const float* w0    = (const float*)d_in[4];
    const float* w1    = (const float*)d_in[5];
    const float* w2    = (const float*)d_in[6];
    const float* w3    = (const float*)d_in[7];
    const float* w4    = (const float*)d_in[8];
    const float* w5    = (const float*)d_in[9];
    float* out = (float*)d_out;
    float* cws = (float*)d_ws;   // 32 k * 2 KB = 64 KB

    hipLaunchKernelGGL(coef_kernel, dim3(Kk), dim3(128), 0, stream,
                       h_idx, w_idx, c_idx, w0, w1, w2, w3, w4, w5, cws);

    dim3 grid(Bb * Kk * 4);   // 2048 blocks: (b, k, strip)
    dim3 block(TPB);
    hipLaunchKernelGGL(logic_conv_kernel, grid, block, 0, stream,
                       x, cws, out);
}